// Round 10
// baseline (3686.611 us; speedup 1.0000x reference)
//
#include <hip/hip_runtime.h>
#include <math.h>

// SAConvLSTM r10: ONE persistent kernel, hand-rolled grid barriers.
// Grid (64,4) = 256 blocks x 256 threads = 1 block/CU (co-resident).
// Shapes: B=4, T=10, Ci=1, Hd=64, H=W=32, S=1024, future=10.
#define SS 1024
#define NBLK 256u

typedef unsigned short u16;
typedef __attribute__((ext_vector_type(8))) __bf16 bf16x8;
typedef __attribute__((ext_vector_type(4))) float f32x4;

#define MFMA(a,b,c) __builtin_amdgcn_mfma_f32_16x16x32_bf16(a,b,c,0,0,0)

__device__ __forceinline__ float sigm(float x){ return 1.f/(1.f+__expf(-x)); }
__device__ __forceinline__ u16 f2b(float x){ return __builtin_bit_cast(u16,(__bf16)x); }
__device__ __forceinline__ float b2f(u16 u){ return (float)__builtin_bit_cast(__bf16,u); }
__device__ __forceinline__ bf16x8 ldb8(const u16* p){ return *(const bf16x8*)p; }
__device__ __forceinline__ void st4b(u16* p, const f32x4 v){
  union { u16 u[4]; uint2 w; } t;
  t.u[0]=f2b(v[0]); t.u[1]=f2b(v[1]); t.u[2]=f2b(v[2]); t.u[3]=f2b(v[3]);
  *(uint2*)p = t.w;
}

// Grid barrier: generation counter, agent scope. All 256 blocks co-resident.
__device__ __forceinline__ void gbar(unsigned* cnt, unsigned* gen) {
  __syncthreads();
  if (threadIdx.x == 0) {
    const unsigned g = __hip_atomic_load(gen, __ATOMIC_RELAXED, __HIP_MEMORY_SCOPE_AGENT);
    if (__hip_atomic_fetch_add(cnt, 1u, __ATOMIC_ACQ_REL, __HIP_MEMORY_SCOPE_AGENT) == NBLK - 1u) {
      __hip_atomic_store(cnt, 0u, __ATOMIC_RELAXED, __HIP_MEMORY_SCOPE_AGENT);
      __hip_atomic_store(gen, g + 1u, __ATOMIC_RELEASE, __HIP_MEMORY_SCOPE_AGENT);
    } else {
      while (__hip_atomic_load(gen, __ATOMIC_ACQUIRE, __HIP_MEMORY_SCOPE_AGENT) == g)
        __builtin_amdgcn_s_sleep(2);
    }
  }
  __syncthreads();
}

__global__ __launch_bounds__(256, 1) void k_all(
    const float* __restrict__ x,
    const float* __restrict__ wconv, const float* __restrict__ bconv,
    const float* __restrict__ wh,    const float* __restrict__ bh,
    const float* __restrict__ wm,    const float* __restrict__ bm,
    const float* __restrict__ wz,    const float* __restrict__ bz,
    const float* __restrict__ wsa,   const float* __restrict__ bsa,
    const float* __restrict__ wco,   const float* __restrict__ bco,
    float* __restrict__ cT, float* __restrict__ mT, float* __restrict__ inp,
    unsigned* __restrict__ bar,
    u16* __restrict__ hTb, u16* __restrict__ mTb, u16* __restrict__ xcat,
    u16* __restrict__ qT, u16* __restrict__ kT, u16* __restrict__ mkT,
    u16* __restrict__ vC, u16* __restrict__ mvC,
    u16* __restrict__ Wg, u16* __restrict__ Whm,
    u16* __restrict__ Wzp, u16* __restrict__ Wsap,
    float* __restrict__ out)
{
  __shared__ u16 hcl[16][72];
  __shared__ u16 ldsP[4*16*72];
  __shared__ float oS[2][16][65];
  __shared__ float mS[2][16], lS[2][16];
  __shared__ u16 zbuf[16][136];
  __shared__ float pool[16][17];

  const int tid = threadIdx.x, wid = tid>>6, lane = tid&63, gl = lane>>4, n = lane&15;
  const int sb = blockIdx.x, b = blockIdx.y, s0 = sb*16;
  const int flatb = b*64 + sb;
  const int s = s0 + n, y = s>>5, xx = s&31;

  // ---- prologue: zero own state; prep weight tiles (1584 elems/block) ----
  for (int i = tid; i < 1024; i += 256) {
    const size_t o4 = ((size_t)b*SS + s0 + (i>>6))*64 + (i&63);
    cT[o4] = 0.f; mT[o4] = 0.f; hTb[o4] = 0; mTb[o4] = 0;
  }
  for (int i = tid; i < 1584; i += 256) {
    const int idx = flatb*1584 + i;
    if (idx < 155648) {                       // Wg [19][256][32]
      const int step = idx >> 13, co = (idx >> 5) & 255, jj = idx & 31;
      float v = 0.f;
      if (step < 18) {
        const int tap = step >> 1, ci = 1 + (step & 1)*32 + jj;
        v = wconv[co*585 + ci*9 + tap];
      } else if (jj < 9) {
        v = wconv[co*585 + jj];
      }
      Wg[idx] = f2b(v);
    } else {
      int l = idx - 155648;
      if (l < 20480) {                        // Whm [2][320][32]
        const int step = l / 10240, row = (l >> 5) % 320, jj = l & 31;
        const int ci = step*32 + jj;
        const float v = (row < 192) ? wh[row*64+ci]*(row < 64 ? 0.125f : 1.f)
                                    : wm[(row-192)*64+ci];
        Whm[l] = f2b(v);
      } else {
        l -= 20480;
        if (l < 8192) {                       // Wzp [4][64][32]
          const int step = l >> 11, co = (l >> 5) & 63, jj = l & 31;
          Wzp[l] = f2b(wz[co*128 + step*32 + jj]);
        } else {
          l -= 8192;                          // Wsap [36][192][32]
          const int step = l / 6144, co = (l >> 5) % 192, jj = l & 31;
          const int tap = step >> 2, ci = (step & 3)*32 + jj;
          Wsap[l] = f2b(wsa[(co*128+ci)*9 + tap]);
        }
      }
    }
  }
  gbar(bar, bar+1);

#pragma unroll 1
  for (int t = 0; t < 20; ++t) {
    const float* xs = (t < 10) ? (x + (size_t)t*SS) : inp;
    const int xbs = (t < 10) ? 10*SS : SS;

    // ================= stage A: gates conv3x3 + 1x1 convs =================
    {
      const u16* hb = hTb + (size_t)b*SS*64;
      f32x4 acc[4];
#pragma unroll
      for (int g4 = 0; g4 < 4; ++g4) {
        const int co = g4*64 + wid*16 + gl*4;
        acc[g4] = (f32x4){ bconv[co], bconv[co+1], bconv[co+2], bconv[co+3] };
      }
      bf16x8 xb;
      {
        union { u16 u[8]; bf16x8 v; } tt;
#pragma unroll
        for (int jj = 0; jj < 8; ++jj) tt.u[jj] = 0;
        if (gl == 0) {
#pragma unroll
          for (int jj = 0; jj < 8; ++jj) {
            const int dy = jj/3 - 1, dx = jj%3 - 1;
            if ((unsigned)(y+dy) < 32u && (unsigned)(xx+dx) < 32u)
              tt.u[jj] = f2b(xs[b*xbs + s + dy*32 + dx]);
          }
        } else if (gl == 1) {
          if (y+1 < 32 && xx+1 < 32) tt.u[0] = f2b(xs[b*xbs + s + 33]);
        }
        xb = tt.v;
      }
#pragma unroll
      for (int step = 0; step < 18; ++step) {
        const int tap = step>>1, half = step&1;
        const int dy = tap/3 - 1, dx = tap%3 - 1;
        const bool ok = ((unsigned)(y+dy) < 32u) & ((unsigned)(xx+dx) < 32u);
        const int sc = ok ? (s + dy*32 + dx) : s;
        bf16x8 bv = ldb8(hb + (size_t)sc*64 + half*32 + gl*8);
        bv = ok ? bv : (bf16x8){};
#pragma unroll
        for (int g4 = 0; g4 < 4; ++g4) {
          const bf16x8 a = ldb8(Wg + step*8192 + (g4*64 + wid*16 + n)*32 + gl*8);
          acc[g4] = MFMA(a, bv, acc[g4]);
        }
      }
#pragma unroll
      for (int g4 = 0; g4 < 4; ++g4) {
        const bf16x8 a = ldb8(Wg + 18*8192 + (g4*64 + wid*16 + n)*32 + gl*8);
        acc[g4] = MFMA(a, xb, acc[g4]);
      }
      const int hd0 = wid*16 + gl*4;
      {
        float* cp = cT + ((size_t)b*SS + s)*64 + hd0;
        f32x4 cv = *(f32x4*)cp, hcv;
#pragma unroll
        for (int rr = 0; rr < 4; ++rr) {
          const float cn = sigm(acc[1][rr])*cv[rr] + sigm(acc[0][rr])*tanhf(acc[3][rr]);
          cv[rr] = cn;
          hcv[rr] = sigm(acc[2][rr])*tanhf(cn);
        }
        *(f32x4*)cp = cv;
        st4b(xcat + ((size_t)b*SS + s)*128 + 64 + hd0, hcv);
        st4b(&hcl[n][hd0], hcv);
      }
      __syncthreads();
      // 1x1 stage
      const int r0 = wid*16, cb = r0 + gl*4;
      f32x4 a1[5];
      a1[0] = (f32x4){ bh[cb]*0.125f, bh[cb+1]*0.125f, bh[cb+2]*0.125f, bh[cb+3]*0.125f };
      a1[1] = (f32x4){ bh[64+cb], bh[64+cb+1], bh[64+cb+2], bh[64+cb+3] };
      a1[2] = (f32x4){ bh[128+cb], bh[128+cb+1], bh[128+cb+2], bh[128+cb+3] };
      a1[3] = (f32x4){ bm[cb], bm[cb+1], bm[cb+2], bm[cb+3] };
      a1[4] = (f32x4){ bm[64+cb], bm[64+cb+1], bm[64+cb+2], bm[64+cb+3] };
#pragma unroll
      for (int step = 0; step < 2; ++step) {
        const bf16x8 bhc = ldb8(&hcl[n][step*32 + gl*8]);
        const bf16x8 bmm = ldb8(mTb + ((size_t)b*SS+s)*64 + step*32 + gl*8);
#pragma unroll
        for (int tt = 0; tt < 5; ++tt) {
          const bf16x8 a = ldb8(Whm + step*10240 + (tt*64 + r0 + n)*32 + gl*8);
          a1[tt] = MFMA(a, tt < 3 ? bhc : bmm, a1[tt]);
        }
      }
      const size_t ps = ((size_t)b*SS + s)*64 + cb;
      st4b(qT + ps, a1[0]);
      st4b(kT + ps, a1[1]);
      st4b(mkT + ps, a1[3]);
#pragma unroll
      for (int rr = 0; rr < 4; ++rr) {
        vC[((size_t)b*64 + cb + rr)*SS + s] = f2b(a1[2][rr]);
        mvC[((size_t)b*64 + cb + rr)*SS + s] = f2b(a1[4][rr]);
      }
    }
    gbar(bar, bar+1);

    // ================= stage B: flash attention (KV-split) + conv_z =======
    {
      const int at = wid & 1, kv = wid >> 1;
      const u16* qb = qT + (size_t)b*SS*64;
      const u16* kb = (at ? mkT : kT) + (size_t)b*SS*64;
      const u16* vb = (at ? mvC : vC) + (size_t)b*64*SS;
      const bf16x8 bq0 = ldb8(qb + (size_t)(s0+n)*64 + gl*8);
      const bf16x8 bq1 = ldb8(qb + (size_t)(s0+n)*64 + 32 + gl*8);
      f32x4 o[4];
#pragma unroll
      for (int ct = 0; ct < 4; ++ct) o[ct] = (f32x4){0.f,0.f,0.f,0.f};
      float mrun = -1e30f, lrun = 0.f;
      u16* pb = ldsP + wid*1152 + n*72;
#pragma unroll 1
      for (int step = 0; step < 8; ++step) {
        const int t0 = kv*512 + step*64;
        f32x4 st4[4];
#pragma unroll
        for (int tt = 0; tt < 4; ++tt) {
          const u16* kr = kb + (size_t)(t0 + tt*16 + n)*64;
          f32x4 a = {0.f,0.f,0.f,0.f};
          a = MFMA(ldb8(kr + gl*8), bq0, a);
          a = MFMA(ldb8(kr + 32 + gl*8), bq1, a);
          st4[tt] = a;
        }
        float mt = -1e30f;
#pragma unroll
        for (int tt = 0; tt < 4; ++tt)
#pragma unroll
          for (int rr = 0; rr < 4; ++rr) mt = fmaxf(mt, st4[tt][rr]);
        mt = fmaxf(mt, __shfl_xor(mt, 16));
        mt = fmaxf(mt, __shfl_xor(mt, 32));
        const float mnew = fmaxf(mrun, mt);
        const float f = __expf(mrun - mnew);
        float ps = 0.f;
#pragma unroll
        for (int tt = 0; tt < 4; ++tt) {
          const float p0e = __expf(st4[tt][0]-mnew), p1e = __expf(st4[tt][1]-mnew);
          const float p2e = __expf(st4[tt][2]-mnew), p3e = __expf(st4[tt][3]-mnew);
          ps += (p0e + p1e) + (p2e + p3e);
          *(unsigned*)(pb + tt*16 + gl*4)     = (unsigned)f2b(p0e) | ((unsigned)f2b(p1e)<<16);
          *(unsigned*)(pb + tt*16 + gl*4 + 2) = (unsigned)f2b(p2e) | ((unsigned)f2b(p3e)<<16);
        }
        ps += __shfl_xor(ps, 16);
        ps += __shfl_xor(ps, 32);
        lrun = lrun*f + ps;
        mrun = mnew;
        float fr[4];
#pragma unroll
        for (int rr = 0; rr < 4; ++rr) fr[rr] = __shfl(f, gl*4 + rr);
#pragma unroll
        for (int ct = 0; ct < 4; ++ct)
#pragma unroll
          for (int rr = 0; rr < 4; ++rr) o[ct][rr] *= fr[rr];
        const bf16x8 pa0 = ldb8(pb + gl*8);
        const bf16x8 pa1 = ldb8(pb + 32 + gl*8);
#pragma unroll
        for (int ct = 0; ct < 4; ++ct) {
          const u16* vr = vb + (size_t)(ct*16 + n)*SS + t0;
          o[ct] = MFMA(pa0, ldb8(vr + gl*8), o[ct]);
          o[ct] = MFMA(pa1, ldb8(vr + 32 + gl*8), o[ct]);
        }
      }
      if (kv == 1) {
#pragma unroll
        for (int ct = 0; ct < 4; ++ct)
#pragma unroll
          for (int rr = 0; rr < 4; ++rr) oS[at][gl*4+rr][ct*16+n] = o[ct][rr];
        if (gl == 0) { mS[at][n] = mrun; lS[at][n] = lrun; }
      }
      __syncthreads();
      if (kv == 0) {
        const float m1 = mS[at][n], l1 = lS[at][n];
        const float mm = fmaxf(mrun, m1);
        const float e0 = __expf(mrun - mm), e1 = __expf(m1 - mm);
        const float inv = 1.f / (lrun*e0 + l1*e1);
        const float a0 = e0*inv, a1v = e1*inv;
        float f0r[4], f1r[4];
#pragma unroll
        for (int rr = 0; rr < 4; ++rr) {
          f0r[rr] = __shfl(a0, gl*4 + rr);
          f1r[rr] = __shfl(a1v, gl*4 + rr);
        }
#pragma unroll
        for (int ct = 0; ct < 4; ++ct)
#pragma unroll
          for (int rr = 0; rr < 4; ++rr)
            zbuf[gl*4+rr][at*64 + ct*16 + n] =
                f2b(o[ct][rr]*f0r[rr] + oS[at][gl*4+rr][ct*16+n]*f1r[rr]);
      }
      __syncthreads();
      const int co = wid*16 + gl*4;
      f32x4 acc = (f32x4){ bz[co], bz[co+1], bz[co+2], bz[co+3] };
#pragma unroll
      for (int qq = 0; qq < 4; ++qq) {
        const bf16x8 bv = ldb8(&zbuf[n][qq*32 + gl*8]);
        const bf16x8 a = ldb8(Wzp + qq*2048 + (wid*16 + n)*32 + gl*8);
        acc = MFMA(a, bv, acc);
      }
      st4b(xcat + ((size_t)b*SS + s0 + n)*128 + co, acc);
      __syncthreads();   // zbuf/oS reuse next cell
    }
    gbar(bar, bar+1);

    // ================= stage C: conv_sa + m,h update + conv_out ===========
    {
      const int mode = (t < 9) ? -1 : (t == 9 ? 0 : 1);
      const int j = t - 10;
      const int hd0 = wid*16 + gl*4;
      f32x4 acc[3];
#pragma unroll
      for (int i = 0; i < 3; ++i) {
        const int co = i*64 + hd0;
        acc[i] = (f32x4){ bsa[co], bsa[co+1], bsa[co+2], bsa[co+3] };
      }
#pragma unroll
      for (int step = 0; step < 36; ++step) {
        const int tap = step>>2, qq = step&3;
        const int dy = tap/3 - 1, dx = tap%3 - 1;
        const bool ok = ((unsigned)(y+dy) < 32u) & ((unsigned)(xx+dx) < 32u);
        const int sc = ok ? (s + dy*32 + dx) : s;
        bf16x8 bv = ldb8(xcat + ((size_t)b*SS + sc)*128 + qq*32 + gl*8);
        bv = ok ? bv : (bf16x8){};
#pragma unroll
        for (int i = 0; i < 3; ++i) {
          const bf16x8 a = ldb8(Wsap + step*6144 + (i*64 + wid*16 + n)*32 + gl*8);
          acc[i] = MFMA(a, bv, acc[i]);
        }
      }
      float* mp = mT + ((size_t)b*SS + s)*64 + hd0;
      f32x4 mv4 = *(f32x4*)mp, hv;
#pragma unroll
      for (int rr = 0; rr < 4; ++rr) {
        const float i2 = sigm(acc[0][rr]);
        const float mn = i2*tanhf(acc[1][rr]) + (1.f - i2)*mv4[rr];
        mv4[rr] = mn;
        hv[rr] = sigm(acc[2][rr])*mn;
      }
      *(f32x4*)mp = mv4;
      st4b(mTb + ((size_t)b*SS + s)*64 + hd0, mv4);
      st4b(hTb + ((size_t)b*SS + s)*64 + hd0, hv);
      if (mode >= 0) {
        pool[n][wid*4 + gl] = hv[0]*wco[hd0] + hv[1]*wco[hd0+1]
                            + hv[2]*wco[hd0+2] + hv[3]*wco[hd0+3];
        __syncthreads();
        if (tid < 16) {
          float v = bco[0];
#pragma unroll
          for (int i = 0; i < 16; ++i) v += pool[tid][i];
          const int sp = s0 + tid;
          if (mode == 1) {
            v = sigm(v);
            out[((size_t)b*10 + j)*SS + sp] = v;
          }
          inp[b*SS + sp] = v;
        }
        __syncthreads();   // pool reuse next cell
      }
    }
    gbar(bar, bar+1);
  }
}

// ---------------------------------------------------------------------------
extern "C" void kernel_launch(void* const* d_in, const int* in_sizes, int n_in,
                              void* d_out, int out_size, void* d_ws, size_t ws_size,
                              hipStream_t stream) {
  const float* x      = (const float*)d_in[0];
  const float* w_conv = (const float*)d_in[1];
  const float* b_conv = (const float*)d_in[2];
  const float* w_h    = (const float*)d_in[3];
  const float* b_h    = (const float*)d_in[4];
  const float* w_m    = (const float*)d_in[5];
  const float* b_m    = (const float*)d_in[6];
  const float* w_z    = (const float*)d_in[7];
  const float* b_z    = (const float*)d_in[8];
  const float* w_sa   = (const float*)d_in[9];
  const float* b_sa   = (const float*)d_in[10];
  const float* w_co   = (const float*)d_in[11];
  const float* b_co   = (const float*)d_in[12];
  float* out = (float*)d_out;

  float* ws  = (float*)d_ws;
  float* cT  = ws;                       // [4][1024][64] fp32
  float* mT  = ws + 262144;
  float* inp = ws + 524288;              // [4][1024]
  unsigned* bar = (unsigned*)(ws + 528384);  // {cnt, gen}
  u16* ub   = (u16*)(ws + 528448);
  u16* hTb  = ub;                        // [4][1024][64] bf16
  u16* mTb  = ub + 262144;
  u16* xcat = ub + 524288;               // [4][1024][128]: Z | hc
  u16* qT   = ub + 1048576;
  u16* kT   = ub + 1310720;
  u16* mkT  = ub + 1572864;
  u16* vC   = ub + 1835008;              // [4][64][1024]
  u16* mvC  = ub + 2097152;
  u16* Wg   = ub + 2359296;              // [19][256][32]
  u16* Whm  = ub + 2514944;              // [2][320][32]
  u16* Wzp  = ub + 2535424;              // [4][64][32]
  u16* Wsap = ub + 2543616;              // [36][192][32]

  hipMemsetAsync(bar, 0, 8, stream);     // barrier state (poisoned 0xAA by harness)

  k_all<<<dim3(64,4), 256, 0, stream>>>(
      x, w_conv, b_conv, w_h, b_h, w_m, b_m, w_z, b_z, w_sa, b_sa, w_co, b_co,
      cT, mT, inp, bar, hTb, mTb, xcat, qT, kT, mkT, vC, mvC,
      Wg, Whm, Wzp, Wsap, out);
}

// Round 11
// 980.814 us; speedup vs baseline: 3.7587x; 3.7587x over previous
//
#include <hip/hip_runtime.h>
#include <math.h>

// SAConvLSTM r11: r9 3-kernel structure + split-K across extra waves
// (A: 8 waves = 4 co x 2 K-halves; B: 4-way KV split; C: 12 waves = 4 hd x 3 K).
// Shapes: B=4, T=10, Ci=1, Hd=64, H=W=32, S=1024, future=10.
#define SS 1024

typedef unsigned short u16;
typedef __attribute__((ext_vector_type(8))) __bf16 bf16x8;
typedef __attribute__((ext_vector_type(4))) float f32x4;

#define MFMA(a,b,c) __builtin_amdgcn_mfma_f32_16x16x32_bf16(a,b,c,0,0,0)

__device__ __forceinline__ float sigm(float x){ return 1.f/(1.f+__expf(-x)); }
__device__ __forceinline__ u16 f2b(float x){ return __builtin_bit_cast(u16,(__bf16)x); }
__device__ __forceinline__ float b2f(u16 u){ return (float)__builtin_bit_cast(__bf16,u); }
__device__ __forceinline__ bf16x8 ldb8(const u16* p){ return *(const bf16x8*)p; }
__device__ __forceinline__ void st4b(u16* p, const f32x4 v){
  union { u16 u[4]; uint2 w; } t;
  t.u[0]=f2b(v[0]); t.u[1]=f2b(v[1]); t.u[2]=f2b(v[2]); t.u[3]=f2b(v[3]);
  *(uint2*)p = t.w;
}

// ---------------------------------------------------------------------------
// Weight prepack (unchanged). bf16 A-tiles [step][co][32].
// ---------------------------------------------------------------------------
__global__ __launch_bounds__(256) void k_prep(
    const float* __restrict__ wconv, const float* __restrict__ wh,
    const float* __restrict__ wm, const float* __restrict__ wz,
    const float* __restrict__ wsa,
    u16* __restrict__ Wg, u16* __restrict__ Whm,
    u16* __restrict__ Wzp, u16* __restrict__ Wsap)
{
  const int idx = blockIdx.x*256 + threadIdx.x;
  if (idx < 155648) {                       // 19*256*32
    const int step = idx >> 13, co = (idx >> 5) & 255, j = idx & 31;
    float v = 0.f;
    if (step < 18) {
      const int tap = step >> 1, ci = 1 + (step & 1)*32 + j;
      v = wconv[co*585 + ci*9 + tap];
    } else if (j < 9) {
      v = wconv[co*585 + j];                // ci=0 (x), tap j
    }
    Wg[idx] = f2b(v);
    return;
  }
  int l = idx - 155648;
  if (l < 20480) {                          // 2*320*32
    const int step = l / 10240, row = (l >> 5) % 320, j = l & 31;
    const int ci = step*32 + j;
    const float v = (row < 192) ? wh[row*64+ci]*(row < 64 ? 0.125f : 1.f)
                                : wm[(row-192)*64+ci];
    Whm[l] = f2b(v);
    return;
  }
  l -= 20480;
  if (l < 8192) {                           // 4*64*32
    const int step = l >> 11, co = (l >> 5) & 63, j = l & 31;
    Wzp[l] = f2b(wz[co*128 + step*32 + j]);
    return;
  }
  l -= 8192;
  if (l < 221184) {                         // 36*192*32
    const int step = l / 6144, co = (l >> 5) % 192, j = l & 31;
    const int tap = step >> 2, ci = (step & 3)*32 + j;
    Wsap[l] = f2b(wsa[(co*128+ci)*9 + tap]);
  }
}

// ---------------------------------------------------------------------------
// K_A: gates conv3x3 (split-K over 2 wave-groups) -> c/hc, then 1x1 convs
// (kh=0 waves: q,k,v from hc LDS; kh=1 waves: mk,mv from m).
// grid (64,4) block 512.
// ---------------------------------------------------------------------------
__global__ __launch_bounds__(512) void k_A(
    const u16* __restrict__ hTb, const float* __restrict__ xsrc, int xbs,
    const u16* __restrict__ Wg, const float* __restrict__ bconv,
    float* __restrict__ cT, u16* __restrict__ xcat,
    const u16* __restrict__ mTb, const u16* __restrict__ Whm,
    const float* __restrict__ bh, const float* __restrict__ bm,
    u16* __restrict__ qT, u16* __restrict__ kT, u16* __restrict__ mkT,
    u16* __restrict__ vC, u16* __restrict__ mvC)
{
  __shared__ u16 hcl[16][72];
  __shared__ float part[4][4][64][4];       // [ww][g4][lane][reg], kh=1 partials
  const int b = blockIdx.y, s0 = blockIdx.x*16;
  const int tid = threadIdx.x, wid = tid>>6, lane = tid&63, gl = lane>>4, n = lane&15;
  const int ww = wid & 3, kh = wid >> 2;
  const u16* hb = hTb + (size_t)b*SS*64;
  const int s = s0 + n, y = s>>5, xx = s&31;
  f32x4 acc[4];
#pragma unroll
  for (int g4 = 0; g4 < 4; ++g4) {
    if (kh == 0) {
      const int co = g4*64 + ww*16 + gl*4;
      acc[g4] = (f32x4){ bconv[co], bconv[co+1], bconv[co+2], bconv[co+3] };
    } else {
      acc[g4] = (f32x4){0.f,0.f,0.f,0.f};
    }
  }
#pragma unroll
  for (int ss = 0; ss < 9; ++ss) {
    const int step = kh*9 + ss;
    const int tap = step>>1, half = step&1;
    const int dy = tap/3 - 1, dx = tap%3 - 1;
    const bool ok = ((unsigned)(y+dy) < 32u) & ((unsigned)(xx+dx) < 32u);
    const int sc = ok ? (s + dy*32 + dx) : s;
    bf16x8 bv = ldb8(hb + (size_t)sc*64 + half*32 + gl*8);
    bv = ok ? bv : (bf16x8){};
#pragma unroll
    for (int g4 = 0; g4 < 4; ++g4) {
      const bf16x8 a = ldb8(Wg + step*8192 + (g4*64 + ww*16 + n)*32 + gl*8);
      acc[g4] = MFMA(a, bv, acc[g4]);
    }
  }
  if (kh == 1) {
    // x step (taps of the input frame, k padded to 32)
    bf16x8 xb;
    {
      union { u16 u[8]; bf16x8 v; } t;
#pragma unroll
      for (int jj = 0; jj < 8; ++jj) t.u[jj] = 0;
      if (gl == 0) {
#pragma unroll
        for (int jj = 0; jj < 8; ++jj) {
          const int dy = jj/3 - 1, dx = jj%3 - 1;
          if ((unsigned)(y+dy) < 32u && (unsigned)(xx+dx) < 32u)
            t.u[jj] = f2b(xsrc[b*xbs + s + dy*32 + dx]);
        }
      } else if (gl == 1) {
        if (y+1 < 32 && xx+1 < 32) t.u[0] = f2b(xsrc[b*xbs + s + 33]);
      }
      xb = t.v;
    }
#pragma unroll
    for (int g4 = 0; g4 < 4; ++g4) {
      const bf16x8 a = ldb8(Wg + 18*8192 + (g4*64 + ww*16 + n)*32 + gl*8);
      acc[g4] = MFMA(a, xb, acc[g4]);
    }
#pragma unroll
    for (int g4 = 0; g4 < 4; ++g4)
      *(f32x4*)&part[ww][g4][lane][0] = acc[g4];
  }
  __syncthreads();
  const int r0 = ww*16, cb = r0 + gl*4;
  if (kh == 0) {
    // combine + LSTM epilogue
#pragma unroll
    for (int g4 = 0; g4 < 4; ++g4) {
      const f32x4 p = *(const f32x4*)&part[ww][g4][lane][0];
      acc[g4][0]+=p[0]; acc[g4][1]+=p[1]; acc[g4][2]+=p[2]; acc[g4][3]+=p[3];
    }
    const int hd0 = cb;
    float* cp = cT + ((size_t)b*SS + s)*64 + hd0;
    f32x4 cv = *(f32x4*)cp, hcv;
#pragma unroll
    for (int rr = 0; rr < 4; ++rr) {
      const float cn = sigm(acc[1][rr])*cv[rr] + sigm(acc[0][rr])*tanhf(acc[3][rr]);
      cv[rr] = cn;
      hcv[rr] = sigm(acc[2][rr])*tanhf(cn);
    }
    *(f32x4*)cp = cv;
    st4b(xcat + ((size_t)b*SS + s)*128 + 64 + hd0, hcv);
    st4b(&hcl[n][hd0], hcv);
  } else {
    // m-path 1x1 (mk, mv) — independent of hc
    f32x4 a3 = (f32x4){ bm[cb], bm[cb+1], bm[cb+2], bm[cb+3] };
    f32x4 a4 = (f32x4){ bm[64+cb], bm[64+cb+1], bm[64+cb+2], bm[64+cb+3] };
#pragma unroll
    for (int step = 0; step < 2; ++step) {
      const bf16x8 bmm = ldb8(mTb + ((size_t)b*SS+s)*64 + step*32 + gl*8);
      a3 = MFMA(ldb8(Whm + step*10240 + (3*64 + r0 + n)*32 + gl*8), bmm, a3);
      a4 = MFMA(ldb8(Whm + step*10240 + (4*64 + r0 + n)*32 + gl*8), bmm, a4);
    }
    const size_t ps = ((size_t)b*SS + s)*64 + cb;
    st4b(mkT + ps, a3);
#pragma unroll
    for (int rr = 0; rr < 4; ++rr)
      mvC[((size_t)b*64 + cb + rr)*SS + s] = f2b(a4[rr]);
  }
  __syncthreads();
  if (kh == 0) {
    // h-path 1x1 (q, k, v) from hcl
    f32x4 a0 = (f32x4){ bh[cb]*0.125f, bh[cb+1]*0.125f, bh[cb+2]*0.125f, bh[cb+3]*0.125f };
    f32x4 a1 = (f32x4){ bh[64+cb], bh[64+cb+1], bh[64+cb+2], bh[64+cb+3] };
    f32x4 a2 = (f32x4){ bh[128+cb], bh[128+cb+1], bh[128+cb+2], bh[128+cb+3] };
#pragma unroll
    for (int step = 0; step < 2; ++step) {
      const bf16x8 bhc = ldb8(&hcl[n][step*32 + gl*8]);
      a0 = MFMA(ldb8(Whm + step*10240 + (0*64 + r0 + n)*32 + gl*8), bhc, a0);
      a1 = MFMA(ldb8(Whm + step*10240 + (1*64 + r0 + n)*32 + gl*8), bhc, a1);
      a2 = MFMA(ldb8(Whm + step*10240 + (2*64 + r0 + n)*32 + gl*8), bhc, a2);
    }
    const size_t ps = ((size_t)b*SS + s)*64 + cb;
    st4b(qT + ps, a0);
    st4b(kT + ps, a1);
#pragma unroll
    for (int rr = 0; rr < 4; ++rr)
      vC[((size_t)b*64 + cb + rr)*SS + s] = f2b(a2[rr]);
  }
}

// ---------------------------------------------------------------------------
// K_B: flash attention, KV split 4-way per attn type (8 waves) + fused conv_z.
// grid (64,4) block 512. wave wid: at = wid&1, kv = wid>>1 (256 keys each).
// ---------------------------------------------------------------------------
__global__ __launch_bounds__(512) void k_B(
    const u16* __restrict__ qT, const u16* __restrict__ kT,
    const u16* __restrict__ mkT, const u16* __restrict__ vC,
    const u16* __restrict__ mvC,
    const u16* __restrict__ Wzp, const float* __restrict__ bz,
    u16* __restrict__ xcat)
{
  __shared__ u16 ldsP[8*16*72];
  __shared__ float oS[2][3][16][65];        // partner partial O
  __shared__ float mS[2][3][16], lS[2][3][16];
  __shared__ u16 zbuf[16][136];
  const int tid = threadIdx.x, wid = tid>>6, lane = tid&63, gl = lane>>4, n = lane&15;
  const int b = blockIdx.y, s0 = blockIdx.x*16;
  const int at = wid & 1, kv = wid >> 1;    // kv in 0..3
  const u16* qb = qT + (size_t)b*SS*64;
  const u16* kb = (at ? mkT : kT) + (size_t)b*SS*64;
  const u16* vb = (at ? mvC : vC) + (size_t)b*64*SS;
  const bf16x8 bq0 = ldb8(qb + (size_t)(s0+n)*64 + gl*8);
  const bf16x8 bq1 = ldb8(qb + (size_t)(s0+n)*64 + 32 + gl*8);
  f32x4 o[4];
#pragma unroll
  for (int ct = 0; ct < 4; ++ct) o[ct] = (f32x4){0.f,0.f,0.f,0.f};
  float mrun = -1e30f, lrun = 0.f;
  u16* pb = ldsP + wid*1152 + n*72;

#pragma unroll 1
  for (int step = 0; step < 4; ++step) {
    const int t0 = kv*256 + step*64;
    f32x4 st4[4];
#pragma unroll
    for (int tt = 0; tt < 4; ++tt) {
      const u16* kr = kb + (size_t)(t0 + tt*16 + n)*64;
      f32x4 a = {0.f,0.f,0.f,0.f};
      a = MFMA(ldb8(kr + gl*8), bq0, a);
      a = MFMA(ldb8(kr + 32 + gl*8), bq1, a);
      st4[tt] = a;
    }
    float mt = -1e30f;
#pragma unroll
    for (int tt = 0; tt < 4; ++tt)
#pragma unroll
      for (int rr = 0; rr < 4; ++rr) mt = fmaxf(mt, st4[tt][rr]);
    mt = fmaxf(mt, __shfl_xor(mt, 16));
    mt = fmaxf(mt, __shfl_xor(mt, 32));
    const float mnew = fmaxf(mrun, mt);
    const float f = __expf(mrun - mnew);
    float ps = 0.f;
#pragma unroll
    for (int tt = 0; tt < 4; ++tt) {
      const float p0e = __expf(st4[tt][0]-mnew), p1e = __expf(st4[tt][1]-mnew);
      const float p2e = __expf(st4[tt][2]-mnew), p3e = __expf(st4[tt][3]-mnew);
      ps += (p0e + p1e) + (p2e + p3e);
      *(unsigned*)(pb + tt*16 + gl*4)     = (unsigned)f2b(p0e) | ((unsigned)f2b(p1e)<<16);
      *(unsigned*)(pb + tt*16 + gl*4 + 2) = (unsigned)f2b(p2e) | ((unsigned)f2b(p3e)<<16);
    }
    ps += __shfl_xor(ps, 16);
    ps += __shfl_xor(ps, 32);
    lrun = lrun*f + ps;
    mrun = mnew;
    float fr[4];
#pragma unroll
    for (int rr = 0; rr < 4; ++rr) fr[rr] = __shfl(f, gl*4 + rr);
#pragma unroll
    for (int ct = 0; ct < 4; ++ct)
#pragma unroll
      for (int rr = 0; rr < 4; ++rr) o[ct][rr] *= fr[rr];
    const bf16x8 pa0 = ldb8(pb + gl*8);
    const bf16x8 pa1 = ldb8(pb + 32 + gl*8);
#pragma unroll
    for (int ct = 0; ct < 4; ++ct) {
      const u16* vr = vb + (size_t)(ct*16 + n)*SS + t0;
      o[ct] = MFMA(pa0, ldb8(vr + gl*8), o[ct]);
      o[ct] = MFMA(pa1, ldb8(vr + 32 + gl*8), o[ct]);
    }
  }
  if (kv > 0) {
#pragma unroll
    for (int ct = 0; ct < 4; ++ct)
#pragma unroll
      for (int rr = 0; rr < 4; ++rr) oS[at][kv-1][gl*4+rr][ct*16+n] = o[ct][rr];
    if (gl == 0) { mS[at][kv-1][n] = mrun; lS[at][kv-1][n] = lrun; }
  }
  __syncthreads();
  if (kv == 0) {
    const float m1 = mS[at][0][n], m2 = mS[at][1][n], m3 = mS[at][2][n];
    const float l1 = lS[at][0][n], l2 = lS[at][1][n], l3 = lS[at][2][n];
    const float mm = fmaxf(fmaxf(mrun, m1), fmaxf(m2, m3));
    const float e0 = __expf(mrun - mm), e1 = __expf(m1 - mm);
    const float e2 = __expf(m2 - mm),   e3 = __expf(m3 - mm);
    const float inv = 1.f / (lrun*e0 + l1*e1 + l2*e2 + l3*e3);
    const float a0 = e0*inv, a1v = e1*inv, a2v = e2*inv, a3v = e3*inv;
    float f0r[4], f1r[4], f2r[4], f3r[4];
#pragma unroll
    for (int rr = 0; rr < 4; ++rr) {
      f0r[rr] = __shfl(a0, gl*4 + rr);
      f1r[rr] = __shfl(a1v, gl*4 + rr);
      f2r[rr] = __shfl(a2v, gl*4 + rr);
      f3r[rr] = __shfl(a3v, gl*4 + rr);
    }
#pragma unroll
    for (int ct = 0; ct < 4; ++ct)
#pragma unroll
      for (int rr = 0; rr < 4; ++rr) {
        const int q = gl*4 + rr, c = ct*16 + n;
        zbuf[q][at*64 + c] = f2b(o[ct][rr]*f0r[rr] + oS[at][0][q][c]*f1r[rr]
                                 + oS[at][1][q][c]*f2r[rr] + oS[at][2][q][c]*f3r[rr]);
      }
  }
  __syncthreads();
  if (wid < 4) {
    const int co = wid*16 + gl*4;
    f32x4 acc = (f32x4){ bz[co], bz[co+1], bz[co+2], bz[co+3] };
#pragma unroll
    for (int qq = 0; qq < 4; ++qq) {
      const bf16x8 bv = ldb8(&zbuf[n][qq*32 + gl*8]);
      const bf16x8 a = ldb8(Wzp + qq*2048 + (wid*16 + n)*32 + gl*8);
      acc = MFMA(a, bv, acc);
    }
    st4b(xcat + ((size_t)b*SS + s0 + n)*128 + co, acc);
  }
}

// ---------------------------------------------------------------------------
// K_C: conv3x3 sa (split-K over 3 wave-groups, 12 waves) -> m,h; fused conv_out.
// grid (64,4) block 768. mode: -1 none, 0 inp only, 1 sigmoid->out[j]+inp.
// ---------------------------------------------------------------------------
__global__ __launch_bounds__(768) void k_C(
    const u16* __restrict__ xcat, const u16* __restrict__ Wsap,
    const float* __restrict__ bsa,
    float* __restrict__ mT, u16* __restrict__ mTb, u16* __restrict__ hTb,
    const float* __restrict__ wco, const float* __restrict__ bco,
    float* __restrict__ inp, float* __restrict__ out, int mode, int j)
{
  __shared__ float part[2][4][3][64][4];    // [kq-1][whd][i][lane][reg]
  __shared__ float pool[16][17];
  const int b = blockIdx.y, s0 = blockIdx.x*16;
  const int tid = threadIdx.x, wid = tid>>6, lane = tid&63, gl = lane>>4, n = lane&15;
  const int whd = wid & 3, kq = wid >> 2;   // kq in 0..2
  const int hd0 = whd*16 + gl*4;
  const int s = s0 + n, y = s>>5, xx = s&31;
  f32x4 acc[3];
#pragma unroll
  for (int i = 0; i < 3; ++i) {
    if (kq == 0) {
      const int co = i*64 + hd0;
      acc[i] = (f32x4){ bsa[co], bsa[co+1], bsa[co+2], bsa[co+3] };
    } else {
      acc[i] = (f32x4){0.f,0.f,0.f,0.f};
    }
  }
#pragma unroll
  for (int ss = 0; ss < 12; ++ss) {
    const int step = kq*12 + ss;
    const int tap = step>>2, qq = step&3;
    const int dy = tap/3 - 1, dx = tap%3 - 1;
    const bool ok = ((unsigned)(y+dy) < 32u) & ((unsigned)(xx+dx) < 32u);
    const int sc = ok ? (s + dy*32 + dx) : s;
    bf16x8 bv = ldb8(xcat + ((size_t)b*SS + sc)*128 + qq*32 + gl*8);
    bv = ok ? bv : (bf16x8){};
#pragma unroll
    for (int i = 0; i < 3; ++i) {
      const bf16x8 a = ldb8(Wsap + step*6144 + (i*64 + whd*16 + n)*32 + gl*8);
      acc[i] = MFMA(a, bv, acc[i]);
    }
  }
  if (kq > 0) {
#pragma unroll
    for (int i = 0; i < 3; ++i)
      *(f32x4*)&part[kq-1][whd][i][lane][0] = acc[i];
  }
  __syncthreads();
  if (kq == 0) {
#pragma unroll
    for (int i = 0; i < 3; ++i) {
      const f32x4 p0 = *(const f32x4*)&part[0][whd][i][lane][0];
      const f32x4 p1 = *(const f32x4*)&part[1][whd][i][lane][0];
      acc[i][0] += p0[0] + p1[0]; acc[i][1] += p0[1] + p1[1];
      acc[i][2] += p0[2] + p1[2]; acc[i][3] += p0[3] + p1[3];
    }
    float* mp = mT + ((size_t)b*SS + s)*64 + hd0;
    f32x4 mv4 = *(f32x4*)mp, hv;
#pragma unroll
    for (int rr = 0; rr < 4; ++rr) {
      const float i2 = sigm(acc[0][rr]);
      const float mn = i2*tanhf(acc[1][rr]) + (1.f - i2)*mv4[rr];
      mv4[rr] = mn;
      hv[rr] = sigm(acc[2][rr])*mn;
    }
    *(f32x4*)mp = mv4;
    st4b(mTb + ((size_t)b*SS + s)*64 + hd0, mv4);
    st4b(hTb + ((size_t)b*SS + s)*64 + hd0, hv);
    if (mode >= 0)
      pool[n][whd*4 + gl] = hv[0]*wco[hd0] + hv[1]*wco[hd0+1]
                          + hv[2]*wco[hd0+2] + hv[3]*wco[hd0+3];
  }
  if (mode >= 0) {
    __syncthreads();
    if (tid < 16) {
      float v = bco[0];
#pragma unroll
      for (int i = 0; i < 16; ++i) v += pool[tid][i];
      const int sp = s0 + tid;
      if (mode == 1) {
        v = sigm(v);
        out[((size_t)b*10 + j)*SS + sp] = v;
      }
      inp[b*SS + sp] = v;
    }
  }
}

// ---------------------------------------------------------------------------
extern "C" void kernel_launch(void* const* d_in, const int* in_sizes, int n_in,
                              void* d_out, int out_size, void* d_ws, size_t ws_size,
                              hipStream_t stream) {
  const float* x      = (const float*)d_in[0];
  const float* w_conv = (const float*)d_in[1];
  const float* b_conv = (const float*)d_in[2];
  const float* w_h    = (const float*)d_in[3];
  const float* b_h    = (const float*)d_in[4];
  const float* w_m    = (const float*)d_in[5];
  const float* b_m    = (const float*)d_in[6];
  const float* w_z    = (const float*)d_in[7];
  const float* b_z    = (const float*)d_in[8];
  const float* w_sa   = (const float*)d_in[9];
  const float* b_sa   = (const float*)d_in[10];
  const float* w_co   = (const float*)d_in[11];
  const float* b_co   = (const float*)d_in[12];
  float* out = (float*)d_out;

  float* ws  = (float*)d_ws;
  float* cT  = ws;                 // [4][1024][64] fp32 pixel-major
  float* mT  = ws + 262144;
  float* inp = ws + 524288;        // [4][1024]
  u16* ub   = (u16*)(ws + 528384);
  u16* hTb  = ub;                  // [4][1024][64] bf16
  u16* mTb  = ub + 262144;
  u16* xcat = ub + 524288;         // [4][1024][128]: Z | hc
  u16* qT   = ub + 1048576;
  u16* kT   = ub + 1310720;
  u16* mkT  = ub + 1572864;
  u16* vC   = ub + 1835008;        // [4][64][1024]
  u16* mvC  = ub + 2097152;
  u16* Wg   = ub + 2359296;        // [19][256][32]
  u16* Whm  = ub + 2514944;        // [2][320][32]
  u16* Wzp  = ub + 2535424;        // [4][64][32]
  u16* Wsap = ub + 2543616;        // [36][192][32]

  hipMemsetAsync(ws, 0, (size_t)524288*4, stream);        // cT, mT = 0
  hipMemsetAsync(hTb, 0, (size_t)524288*2, stream);       // hTb, mTb = 0
  k_prep<<<dim3(1584), 256, 0, stream>>>(w_conv, w_h, w_m, w_z, w_sa, Wg, Whm, Wzp, Wsap);

  auto cell = [&](const float* xsrc, int xbs, int mode, int j) {
    k_A<<<dim3(64,4), 512, 0, stream>>>(hTb, xsrc, xbs, Wg, b_conv, cT, xcat,
                                        mTb, Whm, b_h, b_m, qT, kT, mkT, vC, mvC);
    k_B<<<dim3(64,4), 512, 0, stream>>>(qT, kT, mkT, vC, mvC, Wzp, b_z, xcat);
    k_C<<<dim3(64,4), 768, 0, stream>>>(xcat, Wsap, b_sa, mT, mTb, hTb,
                                        w_co, b_co, inp, out, mode, j);
  };

  for (int t = 0; t < 10; ++t)
    cell(x + (size_t)t*SS, 10*SS, (t == 9) ? 0 : -1, 0);
  for (int j = 0; j < 10; ++j)
    cell(inp, SS, 1, j);
}

// Round 12
// 971.428 us; speedup vs baseline: 3.7950x; 1.0097x over previous
//
#include <hip/hip_runtime.h>
#include <math.h>

// SAConvLSTM r12: r11 + k_B KV-loop full unroll w/ P double-buffer,
// k_A LDS-staged x-patch, memsets folded into k_prep.
// Shapes: B=4, T=10, Ci=1, Hd=64, H=W=32, S=1024, future=10.
#define SS 1024

typedef unsigned short u16;
typedef __attribute__((ext_vector_type(8))) __bf16 bf16x8;
typedef __attribute__((ext_vector_type(4))) float f32x4;

#define MFMA(a,b,c) __builtin_amdgcn_mfma_f32_16x16x32_bf16(a,b,c,0,0,0)

__device__ __forceinline__ float sigm(float x){ return 1.f/(1.f+__expf(-x)); }
__device__ __forceinline__ u16 f2b(float x){ return __builtin_bit_cast(u16,(__bf16)x); }
__device__ __forceinline__ float b2f(u16 u){ return (float)__builtin_bit_cast(__bf16,u); }
__device__ __forceinline__ bf16x8 ldb8(const u16* p){ return *(const bf16x8*)p; }
__device__ __forceinline__ void st4b(u16* p, const f32x4 v){
  union { u16 u[4]; uint2 w; } t;
  t.u[0]=f2b(v[0]); t.u[1]=f2b(v[1]); t.u[2]=f2b(v[2]); t.u[3]=f2b(v[3]);
  *(uint2*)p = t.w;
}

// ---------------------------------------------------------------------------
// Weight prepack + state zeroing. bf16 A-tiles [step][co][32].
// ---------------------------------------------------------------------------
__global__ __launch_bounds__(256) void k_prep(
    const float* __restrict__ wconv, const float* __restrict__ wh,
    const float* __restrict__ wm, const float* __restrict__ wz,
    const float* __restrict__ wsa,
    u16* __restrict__ Wg, u16* __restrict__ Whm,
    u16* __restrict__ Wzp, u16* __restrict__ Wsap,
    float* __restrict__ cT, float* __restrict__ mT,
    u16* __restrict__ hTb, u16* __restrict__ mTb)
{
  const int idx = blockIdx.x*256 + threadIdx.x;
  if (idx < 262144) {                       // zero recurrent state
    cT[idx] = 0.f; mT[idx] = 0.f; hTb[idx] = 0; mTb[idx] = 0;
  }
  if (idx < 155648) {                       // 19*256*32
    const int step = idx >> 13, co = (idx >> 5) & 255, j = idx & 31;
    float v = 0.f;
    if (step < 18) {
      const int tap = step >> 1, ci = 1 + (step & 1)*32 + j;
      v = wconv[co*585 + ci*9 + tap];
    } else if (j < 9) {
      v = wconv[co*585 + j];                // ci=0 (x), tap j
    }
    Wg[idx] = f2b(v);
    return;
  }
  int l = idx - 155648;
  if (l < 20480) {                          // 2*320*32
    const int step = l / 10240, row = (l >> 5) % 320, j = l & 31;
    const int ci = step*32 + j;
    const float v = (row < 192) ? wh[row*64+ci]*(row < 64 ? 0.125f : 1.f)
                                : wm[(row-192)*64+ci];
    Whm[l] = f2b(v);
    return;
  }
  l -= 20480;
  if (l < 8192) {                           // 4*64*32
    const int step = l >> 11, co = (l >> 5) & 63, j = l & 31;
    Wzp[l] = f2b(wz[co*128 + step*32 + j]);
    return;
  }
  l -= 8192;
  if (l < 221184) {                         // 36*192*32
    const int step = l / 6144, co = (l >> 5) % 192, j = l & 31;
    const int tap = step >> 2, ci = (step & 3)*32 + j;
    Wsap[l] = f2b(wsa[(co*128+ci)*9 + tap]);
  }
}

// ---------------------------------------------------------------------------
// K_A: gates conv3x3 (split-K over 2 wave-groups) -> c/hc, then 1x1 convs.
// grid (64,4) block 512. x-patch staged via LDS.
// ---------------------------------------------------------------------------
__global__ __launch_bounds__(512) void k_A(
    const u16* __restrict__ hTb, const float* __restrict__ xsrc, int xbs,
    const u16* __restrict__ Wg, const float* __restrict__ bconv,
    float* __restrict__ cT, u16* __restrict__ xcat,
    const u16* __restrict__ mTb, const u16* __restrict__ Whm,
    const float* __restrict__ bh, const float* __restrict__ bm,
    u16* __restrict__ qT, u16* __restrict__ kT, u16* __restrict__ mkT,
    u16* __restrict__ vC, u16* __restrict__ mvC)
{
  __shared__ u16 hcl[16][72];
  __shared__ float part[4][4][64][4];       // [ww][g4][lane][reg], kh=1 partials
  __shared__ float xtile[3][20];            // x rows y-1..y+1, cols xx0-1..xx0+16
  const int b = blockIdx.y, s0 = blockIdx.x*16;
  const int tid = threadIdx.x, wid = tid>>6, lane = tid&63, gl = lane>>4, n = lane&15;
  const int ww = wid & 3, kh = wid >> 2;
  const u16* hb = hTb + (size_t)b*SS*64;
  const int s = s0 + n, y = s>>5, xx = s&31;
  // stage x tile (zeros at borders)
  if (tid < 60) {
    const int r = tid/20, c = tid%20;
    const int yy = (s0>>5) + r - 1, xc = (s0&31) + c - 1;
    float v = 0.f;
    if ((unsigned)yy < 32u && (unsigned)xc < 32u && c < 18)
      v = xsrc[b*xbs + yy*32 + xc];
    xtile[r][c] = v;
  }
  __syncthreads();
  f32x4 acc[4];
#pragma unroll
  for (int g4 = 0; g4 < 4; ++g4) {
    if (kh == 0) {
      const int co = g4*64 + ww*16 + gl*4;
      acc[g4] = (f32x4){ bconv[co], bconv[co+1], bconv[co+2], bconv[co+3] };
    } else {
      acc[g4] = (f32x4){0.f,0.f,0.f,0.f};
    }
  }
#pragma unroll
  for (int ss = 0; ss < 9; ++ss) {
    const int step = kh*9 + ss;
    const int tap = step>>1, half = step&1;
    const int dy = tap/3 - 1, dx = tap%3 - 1;
    const bool ok = ((unsigned)(y+dy) < 32u) & ((unsigned)(xx+dx) < 32u);
    const int sc = ok ? (s + dy*32 + dx) : s;
    bf16x8 bv = ldb8(hb + (size_t)sc*64 + half*32 + gl*8);
    bv = ok ? bv : (bf16x8){};
#pragma unroll
    for (int g4 = 0; g4 < 4; ++g4) {
      const bf16x8 a = ldb8(Wg + step*8192 + (g4*64 + ww*16 + n)*32 + gl*8);
      acc[g4] = MFMA(a, bv, acc[g4]);
    }
  }
  if (kh == 1) {
    // x step: taps from LDS xtile (k padded to 32)
    bf16x8 xb;
    {
      union { u16 u[8]; bf16x8 v; } t;
#pragma unroll
      for (int jj = 0; jj < 8; ++jj) t.u[jj] = 0;
      if (gl == 0) {
#pragma unroll
        for (int jj = 0; jj < 8; ++jj)
          t.u[jj] = f2b(xtile[jj/3][n + jj%3]);
      } else if (gl == 1) {
        t.u[0] = f2b(xtile[2][n + 2]);
      }
      xb = t.v;
    }
#pragma unroll
    for (int g4 = 0; g4 < 4; ++g4) {
      const bf16x8 a = ldb8(Wg + 18*8192 + (g4*64 + ww*16 + n)*32 + gl*8);
      acc[g4] = MFMA(a, xb, acc[g4]);
    }
#pragma unroll
    for (int g4 = 0; g4 < 4; ++g4)
      *(f32x4*)&part[ww][g4][lane][0] = acc[g4];
  }
  __syncthreads();
  const int r0 = ww*16, cb = r0 + gl*4;
  if (kh == 0) {
    // combine + LSTM epilogue
#pragma unroll
    for (int g4 = 0; g4 < 4; ++g4) {
      const f32x4 p = *(const f32x4*)&part[ww][g4][lane][0];
      acc[g4][0]+=p[0]; acc[g4][1]+=p[1]; acc[g4][2]+=p[2]; acc[g4][3]+=p[3];
    }
    const int hd0 = cb;
    float* cp = cT + ((size_t)b*SS + s)*64 + hd0;
    f32x4 cv = *(f32x4*)cp, hcv;
#pragma unroll
    for (int rr = 0; rr < 4; ++rr) {
      const float cn = sigm(acc[1][rr])*cv[rr] + sigm(acc[0][rr])*tanhf(acc[3][rr]);
      cv[rr] = cn;
      hcv[rr] = sigm(acc[2][rr])*tanhf(cn);
    }
    *(f32x4*)cp = cv;
    st4b(xcat + ((size_t)b*SS + s)*128 + 64 + hd0, hcv);
    st4b(&hcl[n][hd0], hcv);
  } else {
    // m-path 1x1 (mk, mv)
    f32x4 a3 = (f32x4){ bm[cb], bm[cb+1], bm[cb+2], bm[cb+3] };
    f32x4 a4 = (f32x4){ bm[64+cb], bm[64+cb+1], bm[64+cb+2], bm[64+cb+3] };
#pragma unroll
    for (int step = 0; step < 2; ++step) {
      const bf16x8 bmm = ldb8(mTb + ((size_t)b*SS+s)*64 + step*32 + gl*8);
      a3 = MFMA(ldb8(Whm + step*10240 + (3*64 + r0 + n)*32 + gl*8), bmm, a3);
      a4 = MFMA(ldb8(Whm + step*10240 + (4*64 + r0 + n)*32 + gl*8), bmm, a4);
    }
    const size_t ps = ((size_t)b*SS + s)*64 + cb;
    st4b(mkT + ps, a3);
#pragma unroll
    for (int rr = 0; rr < 4; ++rr)
      mvC[((size_t)b*64 + cb + rr)*SS + s] = f2b(a4[rr]);
  }
  __syncthreads();
  if (kh == 0) {
    // h-path 1x1 (q, k, v) from hcl
    f32x4 a0 = (f32x4){ bh[cb]*0.125f, bh[cb+1]*0.125f, bh[cb+2]*0.125f, bh[cb+3]*0.125f };
    f32x4 a1 = (f32x4){ bh[64+cb], bh[64+cb+1], bh[64+cb+2], bh[64+cb+3] };
    f32x4 a2 = (f32x4){ bh[128+cb], bh[128+cb+1], bh[128+cb+2], bh[128+cb+3] };
#pragma unroll
    for (int step = 0; step < 2; ++step) {
      const bf16x8 bhc = ldb8(&hcl[n][step*32 + gl*8]);
      a0 = MFMA(ldb8(Whm + step*10240 + (0*64 + r0 + n)*32 + gl*8), bhc, a0);
      a1 = MFMA(ldb8(Whm + step*10240 + (1*64 + r0 + n)*32 + gl*8), bhc, a1);
      a2 = MFMA(ldb8(Whm + step*10240 + (2*64 + r0 + n)*32 + gl*8), bhc, a2);
    }
    const size_t ps = ((size_t)b*SS + s)*64 + cb;
    st4b(qT + ps, a0);
    st4b(kT + ps, a1);
#pragma unroll
    for (int rr = 0; rr < 4; ++rr)
      vC[((size_t)b*64 + cb + rr)*SS + s] = f2b(a2[rr]);
  }
}

// ---------------------------------------------------------------------------
// K_B: flash attention, KV split 4-way per attn type (8 waves) + fused conv_z.
// grid (64,4) block 512. KV loop fully unrolled, P LDS double-buffered.
// ---------------------------------------------------------------------------
__global__ __launch_bounds__(512) void k_B(
    const u16* __restrict__ qT, const u16* __restrict__ kT,
    const u16* __restrict__ mkT, const u16* __restrict__ vC,
    const u16* __restrict__ mvC,
    const u16* __restrict__ Wzp, const float* __restrict__ bz,
    u16* __restrict__ xcat)
{
  __shared__ u16 ldsP[2*8*16*72];           // double-buffered P
  __shared__ float oS[2][3][16][65];
  __shared__ float mS[2][3][16], lS[2][3][16];
  __shared__ u16 zbuf[16][136];
  const int tid = threadIdx.x, wid = tid>>6, lane = tid&63, gl = lane>>4, n = lane&15;
  const int b = blockIdx.y, s0 = blockIdx.x*16;
  const int at = wid & 1, kv = wid >> 1;    // kv in 0..3
  const u16* qb = qT + (size_t)b*SS*64;
  const u16* kb = (at ? mkT : kT) + (size_t)b*SS*64;
  const u16* vb = (at ? mvC : vC) + (size_t)b*64*SS;
  const bf16x8 bq0 = ldb8(qb + (size_t)(s0+n)*64 + gl*8);
  const bf16x8 bq1 = ldb8(qb + (size_t)(s0+n)*64 + 32 + gl*8);
  f32x4 o[4];
#pragma unroll
  for (int ct = 0; ct < 4; ++ct) o[ct] = (f32x4){0.f,0.f,0.f,0.f};
  float mrun = -1e30f, lrun = 0.f;

#pragma unroll
  for (int step = 0; step < 4; ++step) {
    const int t0 = kv*256 + step*64;
    u16* pb = ldsP + ((step & 1)*8 + wid)*1152 + n*72;
    f32x4 st4[4];
#pragma unroll
    for (int tt = 0; tt < 4; ++tt) {
      const u16* kr = kb + (size_t)(t0 + tt*16 + n)*64;
      f32x4 a = {0.f,0.f,0.f,0.f};
      a = MFMA(ldb8(kr + gl*8), bq0, a);
      a = MFMA(ldb8(kr + 32 + gl*8), bq1, a);
      st4[tt] = a;
    }
    float mt = -1e30f;
#pragma unroll
    for (int tt = 0; tt < 4; ++tt)
#pragma unroll
      for (int rr = 0; rr < 4; ++rr) mt = fmaxf(mt, st4[tt][rr]);
    mt = fmaxf(mt, __shfl_xor(mt, 16));
    mt = fmaxf(mt, __shfl_xor(mt, 32));
    const float mnew = fmaxf(mrun, mt);
    const float f = __expf(mrun - mnew);
    float ps = 0.f;
#pragma unroll
    for (int tt = 0; tt < 4; ++tt) {
      const float p0e = __expf(st4[tt][0]-mnew), p1e = __expf(st4[tt][1]-mnew);
      const float p2e = __expf(st4[tt][2]-mnew), p3e = __expf(st4[tt][3]-mnew);
      ps += (p0e + p1e) + (p2e + p3e);
      *(unsigned*)(pb + tt*16 + gl*4)     = (unsigned)f2b(p0e) | ((unsigned)f2b(p1e)<<16);
      *(unsigned*)(pb + tt*16 + gl*4 + 2) = (unsigned)f2b(p2e) | ((unsigned)f2b(p3e)<<16);
    }
    ps += __shfl_xor(ps, 16);
    ps += __shfl_xor(ps, 32);
    lrun = lrun*f + ps;
    mrun = mnew;
    float fr[4];
#pragma unroll
    for (int rr = 0; rr < 4; ++rr) fr[rr] = __shfl(f, gl*4 + rr);
#pragma unroll
    for (int ct = 0; ct < 4; ++ct)
#pragma unroll
      for (int rr = 0; rr < 4; ++rr) o[ct][rr] *= fr[rr];
    const bf16x8 pa0 = ldb8(pb + gl*8);
    const bf16x8 pa1 = ldb8(pb + 32 + gl*8);
#pragma unroll
    for (int ct = 0; ct < 4; ++ct) {
      const u16* vr = vb + (size_t)(ct*16 + n)*SS + t0;
      o[ct] = MFMA(pa0, ldb8(vr + gl*8), o[ct]);
      o[ct] = MFMA(pa1, ldb8(vr + 32 + gl*8), o[ct]);
    }
  }
  if (kv > 0) {
#pragma unroll
    for (int ct = 0; ct < 4; ++ct)
#pragma unroll
      for (int rr = 0; rr < 4; ++rr) oS[at][kv-1][gl*4+rr][ct*16+n] = o[ct][rr];
    if (gl == 0) { mS[at][kv-1][n] = mrun; lS[at][kv-1][n] = lrun; }
  }
  __syncthreads();
  if (kv == 0) {
    const float m1 = mS[at][0][n], m2 = mS[at][1][n], m3 = mS[at][2][n];
    const float l1 = lS[at][0][n], l2 = lS[at][1][n], l3 = lS[at][2][n];
    const float mm = fmaxf(fmaxf(mrun, m1), fmaxf(m2, m3));
    const float e0 = __expf(mrun - mm), e1 = __expf(m1 - mm);
    const float e2 = __expf(m2 - mm),   e3 = __expf(m3 - mm);
    const float inv = 1.f / (lrun*e0 + l1*e1 + l2*e2 + l3*e3);
    const float a0 = e0*inv, a1v = e1*inv, a2v = e2*inv, a3v = e3*inv;
    float f0r[4], f1r[4], f2r[4], f3r[4];
#pragma unroll
    for (int rr = 0; rr < 4; ++rr) {
      f0r[rr] = __shfl(a0, gl*4 + rr);
      f1r[rr] = __shfl(a1v, gl*4 + rr);
      f2r[rr] = __shfl(a2v, gl*4 + rr);
      f3r[rr] = __shfl(a3v, gl*4 + rr);
    }
#pragma unroll
    for (int ct = 0; ct < 4; ++ct)
#pragma unroll
      for (int rr = 0; rr < 4; ++rr) {
        const int q = gl*4 + rr, c = ct*16 + n;
        zbuf[q][at*64 + c] = f2b(o[ct][rr]*f0r[rr] + oS[at][0][q][c]*f1r[rr]
                                 + oS[at][1][q][c]*f2r[rr] + oS[at][2][q][c]*f3r[rr]);
      }
  }
  __syncthreads();
  if (wid < 4) {
    const int co = wid*16 + gl*4;
    f32x4 acc = (f32x4){ bz[co], bz[co+1], bz[co+2], bz[co+3] };
#pragma unroll
    for (int qq = 0; qq < 4; ++qq) {
      const bf16x8 bv = ldb8(&zbuf[n][qq*32 + gl*8]);
      const bf16x8 a = ldb8(Wzp + qq*2048 + (wid*16 + n)*32 + gl*8);
      acc = MFMA(a, bv, acc);
    }
    st4b(xcat + ((size_t)b*SS + s0 + n)*128 + co, acc);
  }
}

// ---------------------------------------------------------------------------
// K_C: conv3x3 sa (split-K over 3 wave-groups, 12 waves) -> m,h; fused conv_out.
// grid (64,4) block 768. mode: -1 none, 0 inp only, 1 sigmoid->out[j]+inp.
// ---------------------------------------------------------------------------
__global__ __launch_bounds__(768) void k_C(
    const u16* __restrict__ xcat, const u16* __restrict__ Wsap,
    const float* __restrict__ bsa,
    float* __restrict__ mT, u16* __restrict__ mTb, u16* __restrict__ hTb,
    const float* __restrict__ wco, const float* __restrict__ bco,
    float* __restrict__ inp, float* __restrict__ out, int mode, int j)
{
  __shared__ float part[2][4][3][64][4];    // [kq-1][whd][i][lane][reg]
  __shared__ float pool[16][17];
  const int b = blockIdx.y, s0 = blockIdx.x*16;
  const int tid = threadIdx.x, wid = tid>>6, lane = tid&63, gl = lane>>4, n = lane&15;
  const int whd = wid & 3, kq = wid >> 2;   // kq in 0..2
  const int hd0 = whd*16 + gl*4;
  const int s = s0 + n, y = s>>5, xx = s&31;
  f32x4 acc[3];
#pragma unroll
  for (int i = 0; i < 3; ++i) {
    if (kq == 0) {
      const int co = i*64 + hd0;
      acc[i] = (f32x4){ bsa[co], bsa[co+1], bsa[co+2], bsa[co+3] };
    } else {
      acc[i] = (f32x4){0.f,0.f,0.f,0.f};
    }
  }
#pragma unroll
  for (int ss = 0; ss < 12; ++ss) {
    const int step = kq*12 + ss;
    const int tap = step>>2, qq = step&3;
    const int dy = tap/3 - 1, dx = tap%3 - 1;
    const bool ok = ((unsigned)(y+dy) < 32u) & ((unsigned)(xx+dx) < 32u);
    const int sc = ok ? (s + dy*32 + dx) : s;
    bf16x8 bv = ldb8(xcat + ((size_t)b*SS + sc)*128 + qq*32 + gl*8);
    bv = ok ? bv : (bf16x8){};
#pragma unroll
    for (int i = 0; i < 3; ++i) {
      const bf16x8 a = ldb8(Wsap + step*6144 + (i*64 + whd*16 + n)*32 + gl*8);
      acc[i] = MFMA(a, bv, acc[i]);
    }
  }
  if (kq > 0) {
#pragma unroll
    for (int i = 0; i < 3; ++i)
      *(f32x4*)&part[kq-1][whd][i][lane][0] = acc[i];
  }
  __syncthreads();
  if (kq == 0) {
#pragma unroll
    for (int i = 0; i < 3; ++i) {
      const f32x4 p0 = *(const f32x4*)&part[0][whd][i][lane][0];
      const f32x4 p1 = *(const f32x4*)&part[1][whd][i][lane][0];
      acc[i][0] += p0[0] + p1[0]; acc[i][1] += p0[1] + p1[1];
      acc[i][2] += p0[2] + p1[2]; acc[i][3] += p0[3] + p1[3];
    }
    float* mp = mT + ((size_t)b*SS + s)*64 + hd0;
    f32x4 mv4 = *(f32x4*)mp, hv;
#pragma unroll
    for (int rr = 0; rr < 4; ++rr) {
      const float i2 = sigm(acc[0][rr]);
      const float mn = i2*tanhf(acc[1][rr]) + (1.f - i2)*mv4[rr];
      mv4[rr] = mn;
      hv[rr] = sigm(acc[2][rr])*mn;
    }
    *(f32x4*)mp = mv4;
    st4b(mTb + ((size_t)b*SS + s)*64 + hd0, mv4);
    st4b(hTb + ((size_t)b*SS + s)*64 + hd0, hv);
    if (mode >= 0)
      pool[n][whd*4 + gl] = hv[0]*wco[hd0] + hv[1]*wco[hd0+1]
                          + hv[2]*wco[hd0+2] + hv[3]*wco[hd0+3];
  }
  if (mode >= 0) {
    __syncthreads();
    if (tid < 16) {
      float v = bco[0];
#pragma unroll
      for (int i = 0; i < 16; ++i) v += pool[tid][i];
      const int sp = s0 + tid;
      if (mode == 1) {
        v = sigm(v);
        out[((size_t)b*10 + j)*SS + sp] = v;
      }
      inp[b*SS + sp] = v;
    }
  }
}

// ---------------------------------------------------------------------------
extern "C" void kernel_launch(void* const* d_in, const int* in_sizes, int n_in,
                              void* d_out, int out_size, void* d_ws, size_t ws_size,
                              hipStream_t stream) {
  const float* x      = (const float*)d_in[0];
  const float* w_conv = (const float*)d_in[1];
  const float* b_conv = (const float*)d_in[2];
  const float* w_h    = (const float*)d_in[3];
  const float* b_h    = (const float*)d_in[4];
  const float* w_m    = (const float*)d_in[5];
  const float* b_m    = (const float*)d_in[6];
  const float* w_z    = (const float*)d_in[7];
  const float* b_z    = (const float*)d_in[8];
  const float* w_sa   = (const float*)d_in[9];
  const float* b_sa   = (const float*)d_in[10];
  const float* w_co   = (const float*)d_in[11];
  const float* b_co   = (const float*)d_in[12];
  float* out = (float*)d_out;

  float* ws  = (float*)d_ws;
  float* cT  = ws;                 // [4][1024][64] fp32 pixel-major
  float* mT  = ws + 262144;
  float* inp = ws + 524288;        // [4][1024]
  u16* ub   = (u16*)(ws + 528384);
  u16* hTb  = ub;                  // [4][1024][64] bf16
  u16* mTb  = ub + 262144;
  u16* xcat = ub + 524288;         // [4][1024][128]: Z | hc
  u16* qT   = ub + 1048576;
  u16* kT   = ub + 1310720;
  u16* mkT  = ub + 1572864;
  u16* vC   = ub + 1835008;        // [4][64][1024]
  u16* mvC  = ub + 2097152;
  u16* Wg   = ub + 2359296;        // [19][256][32]
  u16* Whm  = ub + 2514944;        // [2][320][32]
  u16* Wzp  = ub + 2535424;        // [4][64][32]
  u16* Wsap = ub + 2543616;        // [36][192][32]

  k_prep<<<dim3(1584), 256, 0, stream>>>(w_conv, w_h, w_m, w_z, w_sa,
                                         Wg, Whm, Wzp, Wsap, cT, mT, hTb, mTb);

  auto cell = [&](const float* xsrc, int xbs, int mode, int j) {
    k_A<<<dim3(64,4), 512, 0, stream>>>(hTb, xsrc, xbs, Wg, b_conv, cT, xcat,
                                        mTb, Whm, b_h, b_m, qT, kT, mkT, vC, mvC);
    k_B<<<dim3(64,4), 512, 0, stream>>>(qT, kT, mkT, vC, mvC, Wzp, b_z, xcat);
    k_C<<<dim3(64,4), 768, 0, stream>>>(xcat, Wsap, b_sa, mT, mTb, hTb,
                                        w_co, b_co, inp, out, mode, j);
  };

  for (int t = 0; t < 10; ++t)
    cell(x + (size_t)t*SS, 10*SS, (t == 9) ? 0 : -1, 0);
  for (int j = 0; j < 10; ++j)
    cell(inp, SS, 1, j);
}